// Round 1
// baseline (8285.618 us; speedup 1.0000x reference)
//
#include <hip/hip_runtime.h>

#define BN_ 8
#define CIN 256
#define CMID 128
#define COUT 256
#define HH 128
#define WW 128

#define NEG_INF (-3.402823466e+38f)

// LDS layout (floats). xs/wf live during the conv K-loop; ybuf aliases them after.
#define XS_F (8*3*132)        // 3168: [ci 8][row 3][col 132] (col = w+1, zero-padded)
#define WF_F (8*3*64*4)       // 6144: [(i*3+kh)][p 64][kw padded to 4]
#define YB_F (64*128)         // 8192
#define SM_F 9312             // max(XS_F+WF_F, YB_F)

// MODE 0: two branches (A=left reverse-scan, B=right forward-scan), 32ch each,
//         fused row cummax, writes sbuf = scanA + scanB. grid (4,128,8).
// MODE 1: single branch A, 64ch per block, writes BN+ReLU conv result to yA.
//         grid (2,128,8).
template<int MODE>
__global__ void __launch_bounds__(256)
branch_conv_kernel(const float* __restrict__ x,
                   const float* __restrict__ wA, const float* __restrict__ scA, const float* __restrict__ shA,
                   const float* __restrict__ wB, const float* __restrict__ scB, const float* __restrict__ shB,
                   float* __restrict__ sbuf, float* __restrict__ yA)
{
    __shared__ float smem[SM_F];
    float* xs   = smem;
    float* wf   = smem + XS_F;
    float* ybuf = smem;          // aliases xs/wf after conv loop

    const int t   = threadIdx.x;
    const int cc  = blockIdx.x;
    const int h   = blockIdx.y;
    const int b   = blockIdx.z;
    const int co0 = (MODE == 0) ? cc * 32 : cc * 64;
    const int wt  = t & 15;      // w tile: w = wt*8 + wj
    const int pt  = t >> 4;      // pair tile: p = pt*4 + cj

    float acc[4][8];
#pragma unroll
    for (int cj = 0; cj < 4; ++cj)
#pragma unroll
        for (int wj = 0; wj < 8; ++wj) acc[cj][wj] = 0.f;

    for (int ci0 = 0; ci0 < CIN; ci0 += 8) {
        __syncthreads();
        // stage x: rows h-1..h+1, cols -1..130 (zero pad)
        for (int idx = t; idx < XS_F; idx += 256) {
            int i   = idx / 396;
            int rem = idx - i * 396;
            int r   = rem / 132;
            int col = rem - r * 132;
            int ih = h + r - 1;
            int iw = col - 1;
            float v = 0.f;
            if (ih >= 0 && ih < HH && iw >= 0 && iw < WW)
                v = x[(((size_t)b * CIN + ci0 + i) * HH + ih) * WW + iw];
            xs[idx] = v;
        }
        // stage weights
        for (int idx = t; idx < 64 * 72; idx += 256) {
            int p   = idx / 72;
            int rem = idx - p * 72;
            int i   = rem / 9;
            int k   = rem - i * 9;
            int kh  = k / 3, kw = k - kh * 3;
            int chl = (MODE == 0) ? (co0 + (p & 31)) : (co0 + p);
            const float* wsrc = (MODE == 0 && (p & 32)) ? wB : wA;
            wf[((i * 3 + kh) * 64 + p) * 4 + kw] =
                wsrc[((size_t)chl * CIN + ci0 + i) * 9 + k];
        }
        __syncthreads();
#pragma unroll
        for (int i = 0; i < 8; ++i) {
#pragma unroll
            for (int kh = 0; kh < 3; ++kh) {
                const float* xrow = &xs[(i * 3 + kh) * 132 + wt * 8];
                float xv[10];
#pragma unroll
                for (int j = 0; j < 10; ++j) xv[j] = xrow[j];
                const float* wrow = &wf[((i * 3 + kh) * 64 + pt * 4) * 4];
#pragma unroll
                for (int cj = 0; cj < 4; ++cj) {
                    float w0 = wrow[cj * 4 + 0];
                    float w1 = wrow[cj * 4 + 1];
                    float w2 = wrow[cj * 4 + 2];
#pragma unroll
                    for (int wj = 0; wj < 8; ++wj)
                        acc[cj][wj] = fmaf(w2, xv[wj + 2],
                                      fmaf(w1, xv[wj + 1],
                                      fmaf(w0, xv[wj], acc[cj][wj])));
                }
            }
        }
    }
    __syncthreads();   // xs/wf dead; ybuf aliases them

    // BN + ReLU -> ybuf
#pragma unroll
    for (int cj = 0; cj < 4; ++cj) {
        int p   = pt * 4 + cj;
        int chl = (MODE == 0) ? (co0 + (p & 31)) : (co0 + p);
        float sc, sh;
        if (MODE == 0 && (p & 32)) { sc = scB[chl]; sh = shB[chl]; }
        else                       { sc = scA[chl]; sh = shA[chl]; }
#pragma unroll
        for (int wj = 0; wj < 8; ++wj) {
            float v = fmaf(acc[cj][wj], sc, sh);
            ybuf[p * 128 + wt * 8 + wj] = fmaxf(v, 0.f);
        }
    }
    __syncthreads();

    if (MODE == 0) {
        // rows p<32: branch A (left) reverse cummax; p>=32: branch B (right) forward
        const int wave = t >> 6, lane = t & 63;
        for (int r = 0; r < 16; ++r) {
            int p = wave * 16 + r;                 // wave-uniform branch below
            float v0 = ybuf[p * 128 + 2 * lane];
            float v1 = ybuf[p * 128 + 2 * lane + 1];
            float a = fmaxf(v0, v1);
            if (p >= 32) {                         // forward (max over w' <= w)
#pragma unroll
                for (int d = 1; d < 64; d <<= 1) {
                    float o = __shfl_up(a, d);
                    if (lane >= d) a = fmaxf(a, o);
                }
                float e = __shfl_up(a, 1);
                if (lane == 0) e = NEG_INF;
                float o0 = fmaxf(e, v0);
                float o1 = fmaxf(o0, v1);
                ybuf[p * 128 + 2 * lane]     = o0;
                ybuf[p * 128 + 2 * lane + 1] = o1;
            } else {                               // reverse (max over w' >= w)
#pragma unroll
                for (int d = 1; d < 64; d <<= 1) {
                    float o = __shfl_down(a, d);
                    if (lane < 64 - d) a = fmaxf(a, o);
                }
                float e = __shfl_down(a, 1);
                if (lane == 63) e = NEG_INF;
                float o1 = fmaxf(e, v1);
                float o0 = fmaxf(o1, v0);
                ybuf[p * 128 + 2 * lane]     = o0;
                ybuf[p * 128 + 2 * lane + 1] = o1;
            }
        }
        __syncthreads();
        for (int idx = t; idx < 32 * 128; idx += 256) {
            int cl = idx >> 7, w = idx & 127;
            float v = ybuf[cl * 128 + w] + ybuf[(32 + cl) * 128 + w];
            sbuf[(((size_t)b * CMID + co0 + cl) * HH + h) * WW + w] = v;
        }
    } else {
        for (int idx = t; idx < 64 * 128; idx += 256) {
            int p = idx >> 7, w = idx & 127;
            yA[(((size_t)b * CMID + co0 + p) * HH + h) * WW + w] = ybuf[idx];
        }
    }
}

// Column cummax over h (REVERSE=1: max over h'>=h), accumulate into sbuf.
template<int REVERSE>
__global__ void __launch_bounds__(128)
colscan_kernel(const float* __restrict__ y, float* __restrict__ sbuf)
{
    const int w = threadIdx.x;
    const int c = blockIdx.x;
    const int b = blockIdx.y;
    size_t base = ((size_t)b * CMID + c) * HH * WW + w;
    float cur = NEG_INF;
    if (REVERSE) {
#pragma unroll 4
        for (int h = HH - 1; h >= 0; --h) {
            cur = fmaxf(cur, y[base + (size_t)h * WW]);
            sbuf[base + (size_t)h * WW] += cur;
        }
    } else {
#pragma unroll 4
        for (int h = 0; h < HH; ++h) {
            cur = fmaxf(cur, y[base + (size_t)h * WW]);
            sbuf[base + (size_t)h * WW] += cur;
        }
    }
}

// Final: conv3x3(sbuf,128->256)*s2+o2 + conv1x1(x,256->256)*s1+o1, ReLU.
__global__ void __launch_bounds__(256)
final_conv_kernel(const float* __restrict__ sbuf, const float* __restrict__ x,
                  const float* __restrict__ w2, const float* __restrict__ s2, const float* __restrict__ o2,
                  const float* __restrict__ w1, const float* __restrict__ s1, const float* __restrict__ o1,
                  float* __restrict__ out)
{
    __shared__ float smem[SM_F];
    float* xs   = smem;
    float* wf   = smem + XS_F;
    float* ybuf = smem;

    const int t   = threadIdx.x;
    const int cc  = blockIdx.x;      // 0..3 -> 64 out ch each
    const int h   = blockIdx.y;
    const int b   = blockIdx.z;
    const int co0 = cc * 64;
    const int wt  = t & 15;
    const int pt  = t >> 4;

    float acc2[4][8], acc1[4][8];
#pragma unroll
    for (int cj = 0; cj < 4; ++cj)
#pragma unroll
        for (int wj = 0; wj < 8; ++wj) { acc2[cj][wj] = 0.f; acc1[cj][wj] = 0.f; }

    // 3x3 over sbuf (CMID input channels)
    for (int ci0 = 0; ci0 < CMID; ci0 += 8) {
        __syncthreads();
        for (int idx = t; idx < XS_F; idx += 256) {
            int i   = idx / 396;
            int rem = idx - i * 396;
            int r   = rem / 132;
            int col = rem - r * 132;
            int ih = h + r - 1;
            int iw = col - 1;
            float v = 0.f;
            if (ih >= 0 && ih < HH && iw >= 0 && iw < WW)
                v = sbuf[(((size_t)b * CMID + ci0 + i) * HH + ih) * WW + iw];
            xs[idx] = v;
        }
        for (int idx = t; idx < 64 * 72; idx += 256) {
            int p   = idx / 72;
            int rem = idx - p * 72;
            int i   = rem / 9;
            int k   = rem - i * 9;
            int kh  = k / 3, kw = k - kh * 3;
            wf[((i * 3 + kh) * 64 + p) * 4 + kw] =
                w2[((size_t)(co0 + p) * CMID + ci0 + i) * 9 + k];
        }
        __syncthreads();
#pragma unroll
        for (int i = 0; i < 8; ++i) {
#pragma unroll
            for (int kh = 0; kh < 3; ++kh) {
                const float* xrow = &xs[(i * 3 + kh) * 132 + wt * 8];
                float xv[10];
#pragma unroll
                for (int j = 0; j < 10; ++j) xv[j] = xrow[j];
                const float* wrow = &wf[((i * 3 + kh) * 64 + pt * 4) * 4];
#pragma unroll
                for (int cj = 0; cj < 4; ++cj) {
                    float w0 = wrow[cj * 4 + 0];
                    float w1_ = wrow[cj * 4 + 1];
                    float w2_ = wrow[cj * 4 + 2];
#pragma unroll
                    for (int wj = 0; wj < 8; ++wj)
                        acc2[cj][wj] = fmaf(w2_, xv[wj + 2],
                                       fmaf(w1_, xv[wj + 1],
                                       fmaf(w0, xv[wj], acc2[cj][wj])));
                }
            }
        }
    }

    // 1x1 over x (CIN input channels); reuse smem: xr [16][128], wf1 [16][64]
    float* xr  = smem;
    float* wf1 = smem + 16 * 128;
    for (int ci0 = 0; ci0 < CIN; ci0 += 16) {
        __syncthreads();
        for (int idx = t; idx < 16 * 128; idx += 256) {
            int i = idx >> 7, w = idx & 127;
            xr[idx] = x[(((size_t)b * CIN + ci0 + i) * HH + h) * WW + w];
        }
        for (int idx = t; idx < 16 * 64; idx += 256) {
            int i = idx >> 6, p = idx & 63;
            wf1[idx] = w1[(size_t)(co0 + p) * CIN + ci0 + i];
        }
        __syncthreads();
#pragma unroll
        for (int i = 0; i < 16; ++i) {
            float xv[8];
#pragma unroll
            for (int j = 0; j < 8; ++j) xv[j] = xr[i * 128 + wt * 8 + j];
#pragma unroll
            for (int cj = 0; cj < 4; ++cj) {
                float wv = wf1[i * 64 + pt * 4 + cj];
#pragma unroll
                for (int wj = 0; wj < 8; ++wj)
                    acc1[cj][wj] = fmaf(wv, xv[wj], acc1[cj][wj]);
            }
        }
    }
    __syncthreads();

#pragma unroll
    for (int cj = 0; cj < 4; ++cj) {
        int p  = pt * 4 + cj;
        int co = co0 + p;
        float a2s = s2[co], a2o = o2[co], a1s = s1[co], a1o = o1[co];
#pragma unroll
        for (int wj = 0; wj < 8; ++wj) {
            float v = fmaf(acc2[cj][wj], a2s, a2o) + fmaf(acc1[cj][wj], a1s, a1o);
            ybuf[p * 128 + wt * 8 + wj] = fmaxf(v, 0.f);
        }
    }
    __syncthreads();
    for (int idx = t; idx < 64 * 128; idx += 256) {
        int p = idx >> 7, w = idx & 127;
        out[(((size_t)b * COUT + co0 + p) * HH + h) * WW + w] = ybuf[idx];
    }
}

extern "C" void kernel_launch(void* const* d_in, const int* in_sizes, int n_in,
                              void* d_out, int out_size, void* d_ws, size_t ws_size,
                              hipStream_t stream)
{
    const float* x   = (const float*)d_in[0];
    const float* w_l = (const float*)d_in[1];
    const float* s_l = (const float*)d_in[2];
    const float* o_l = (const float*)d_in[3];
    const float* w_r = (const float*)d_in[4];
    const float* s_r = (const float*)d_in[5];
    const float* o_r = (const float*)d_in[6];
    const float* w_t = (const float*)d_in[7];
    const float* s_t = (const float*)d_in[8];
    const float* o_t = (const float*)d_in[9];
    const float* w_b = (const float*)d_in[10];
    const float* s_b = (const float*)d_in[11];
    const float* o_b = (const float*)d_in[12];
    const float* w2  = (const float*)d_in[13];
    const float* s2  = (const float*)d_in[14];
    const float* o2  = (const float*)d_in[15];
    const float* w1  = (const float*)d_in[16];
    const float* s1  = (const float*)d_in[17];
    const float* o1  = (const float*)d_in[18];
    float* out = (float*)d_out;
    float* ws  = (float*)d_ws;

    // scratch: sbuf (8*128*128*128 fl = 64 MiB) + ybr (64 MiB) = 128 MiB total
    float* sbuf = ws;
    float* ybr  = ws + (size_t)16777216;

    dim3 blk(256);
    // L+R conv+BN+ReLU + fused row scans -> sbuf = xl + xr
    branch_conv_kernel<0><<<dim3(4, 128, 8), blk, 0, stream>>>(
        x, w_l, s_l, o_l, w_r, s_r, o_r, sbuf, nullptr);
    // T branch conv -> ybr; reverse column scan, sbuf += xt
    branch_conv_kernel<1><<<dim3(2, 128, 8), blk, 0, stream>>>(
        x, w_t, s_t, o_t, nullptr, nullptr, nullptr, nullptr, ybr);
    colscan_kernel<1><<<dim3(128, 8), dim3(128), 0, stream>>>(ybr, sbuf);
    // B branch conv -> ybr; forward column scan, sbuf += xb
    branch_conv_kernel<1><<<dim3(2, 128, 8), blk, 0, stream>>>(
        x, w_b, s_b, o_b, nullptr, nullptr, nullptr, nullptr, ybr);
    colscan_kernel<0><<<dim3(128, 8), dim3(128), 0, stream>>>(ybr, sbuf);
    // final fused conv3x3 + conv1x1 + ReLU
    final_conv_kernel<<<dim3(4, 128, 8), blk, 0, stream>>>(
        sbuf, x, w2, s2, o2, w1, s1, o1, out);
}

// Round 2
// 1362.991 us; speedup vs baseline: 6.0790x; 6.0790x over previous
//
#include <hip/hip_runtime.h>

#define HHH 128
#define WWW 128
#define NEG_INF (-3.402823466e+38f)

typedef __bf16 bf16x8 __attribute__((ext_vector_type(8)));
typedef float  f32x16 __attribute__((ext_vector_type(16)));

__device__ __forceinline__ unsigned short f2bf(float f){
    unsigned u = __builtin_bit_cast(unsigned, f);
    u += 0x7fffu + ((u >> 16) & 1u);
    return (unsigned short)(u >> 16);
}
__device__ __forceinline__ float bf2f(unsigned short h){
    unsigned u = ((unsigned)h) << 16;
    return __builtin_bit_cast(float, u);
}

// ---------------- prep: x fp32 NCHW -> bf16 NHWC -------------------
__global__ void __launch_bounds__(256)
k_xpose(const float* __restrict__ x, unsigned short* __restrict__ xh)
{
    __shared__ float tile[64 * 129];
    const int t = threadIdx.x;
    const int ci0 = blockIdx.x * 64, h = blockIdx.y, b = blockIdx.z;
    const float4* src = (const float4*)x;
#pragma unroll
    for (int i = 0; i < 8; ++i) {
        int idx = t + i * 256;            // 2048 float4
        int ci = idx >> 5, w4 = idx & 31;
        float4 v = src[((b * 256 + ci0 + ci) * 128 + h) * 32 + w4];
        tile[ci * 129 + w4 * 4 + 0] = v.x;
        tile[ci * 129 + w4 * 4 + 1] = v.y;
        tile[ci * 129 + w4 * 4 + 2] = v.z;
        tile[ci * 129 + w4 * 4 + 3] = v.w;
    }
    __syncthreads();
    unsigned* dst = (unsigned*)xh;
#pragma unroll
    for (int i = 0; i < 16; ++i) {
        int idx = t + i * 256;            // 4096 uint (2 bf16 each)
        int w = idx >> 5, cp = idx & 31;
        float lo = tile[(cp * 2 + 0) * 129 + w];
        float hi = tile[(cp * 2 + 1) * 129 + w];
        dst[((b * 128 + h) * 128 + w) * 128 + (ci0 >> 1) + cp] =
            (unsigned)f2bf(lo) | ((unsigned)f2bf(hi) << 16);
    }
}

// ---------------- prep: weight packing (BN scale folded) -----------
// wpkBR elem: ((ciblk*36 + k9*4 + ((ci>>3)&3))*512 + p)*8 + (ci&7), p=(c>>4)*64+br*16+(c&15)
// wpk2  elem: ((ciblk*36 + k9*4 + ((ci>>3)&3))*256... (256 co): *2048 + c*8 + (ci&7)
// wpk1  elem: ((ci>>5)*4 + ((ci>>3)&3))*2048 + c*8 + (ci&7)
__global__ void __launch_bounds__(256)
k_wpack(const float* __restrict__ wl, const float* __restrict__ sl, const float* __restrict__ ol,
        const float* __restrict__ wr, const float* __restrict__ sr, const float* __restrict__ orr,
        const float* __restrict__ wt, const float* __restrict__ st, const float* __restrict__ ot,
        const float* __restrict__ wb, const float* __restrict__ sb, const float* __restrict__ ob,
        const float* __restrict__ w2, const float* __restrict__ s2, const float* __restrict__ o2,
        const float* __restrict__ w1, const float* __restrict__ s1, const float* __restrict__ o1,
        unsigned short* __restrict__ wpkBR, unsigned short* __restrict__ wpk2,
        unsigned short* __restrict__ wpk1, float* __restrict__ shF, float* __restrict__ obF)
{
    int i = blockIdx.x * 256 + threadIdx.x;
    if (i < 1179648) {
        int br = i / 294912, r = i % 294912;
        int c = r / 2304, r2 = r % 2304, ci = r2 / 9, k9 = r2 % 9;
        const float* wp = br == 0 ? wl : br == 1 ? wr : br == 2 ? wt : wb;
        const float* sp = br == 0 ? sl : br == 1 ? sr : br == 2 ? st : sb;
        float v = wp[r] * sp[c];
        int p = (c >> 4) * 64 + br * 16 + (c & 15);
        wpkBR[(((ci >> 5) * 36 + k9 * 4 + ((ci >> 3) & 3)) * 512 + p) * 8 + (ci & 7)] = f2bf(v);
    } else if (i < 1474560) {
        int j = i - 1179648;
        int c = j / 1152, r2 = j % 1152, ci = r2 / 9, k9 = r2 % 9;
        float v = w2[j] * s2[c];
        wpk2[((ci >> 5) * 36 + k9 * 4 + ((ci >> 3) & 3)) * 2048 + c * 8 + (ci & 7)] = f2bf(v);
    } else if (i < 1540096) {
        int j = i - 1474560;
        int c = j >> 8, ci = j & 255;
        float v = w1[j] * s1[c];
        wpk1[((ci >> 5) * 4 + ((ci >> 3) & 3)) * 2048 + c * 8 + (ci & 7)] = f2bf(v);
    } else if (i < 1540608) {
        int p = i - 1540096;
        int br = (p >> 4) & 3, c = (p >> 6) * 16 + (p & 15);
        const float* op = br == 0 ? ol : br == 1 ? orr : br == 2 ? ot : ob;
        shF[p] = op[c];
    } else if (i < 1540864) {
        int c = i - 1540608;
        obF[c] = o2[c] + o1[c];
    }
}

// ---------------- branch conv: all 4 branches, MFMA ----------------
// grid (8 co-chunks, 128 h, 8 b), 256 thr. M=64 rows (4br x 16ch), N=128 w, K=2304.
#define XST_US (3*2*132*24)        // 19008 ushort = 38016 B, pad 24/col
#define WLD_US (36*64*8)           // 18432 ushort = 36864 B
__global__ void __launch_bounds__(256, 2)
k_brconv(const unsigned short* __restrict__ xh, const unsigned short* __restrict__ wpkBR,
         const float* __restrict__ shF, unsigned short* __restrict__ sbuf2,
         unsigned short* __restrict__ ytbT, unsigned short* __restrict__ ytbB)
{
    __shared__ __align__(16) char smem[75136];
    unsigned short* xst  = (unsigned short*)smem;
    unsigned short* wlds = (unsigned short*)(smem + 38016);
    float* shs  = (float*)(smem + 74880);
    float* ybuf = (float*)smem;                      // aliases xst/wlds after K-loop

    const int t = threadIdx.x;
    const int bx = blockIdx.x, h = blockIdx.y, b = blockIdx.z;
    const int wv = t >> 6, lane = t & 63;
    const int lo5 = lane & 31, hi1 = lane >> 5;

    if (t < 64) shs[t] = shF[bx * 64 + t];

    f32x16 acc0, acc1;
#pragma unroll
    for (int i = 0; i < 16; ++i) { acc0[i] = 0.f; acc1[i] = 0.f; }

    const uint4* wsrc4 = (const uint4*)wpkBR;
    for (int ciblk = 0; ciblk < 8; ++ciblk) {
        __syncthreads();
        // stage input patches: [rk=r*2+khalf][col 132][khi*8] (pad 24/col)
        for (int idx = t; idx < 1584; idx += 256) {
            int khi = idx & 1, tmp = idx >> 1;
            int col = tmp % 132, rk = tmp / 132;
            int r = rk >> 1, khalf = rk & 1;
            int ih = h + r - 1, iw = col - 1;
            uint4 v = make_uint4(0, 0, 0, 0);
            if (ih >= 0 && ih < 128 && iw >= 0 && iw < 128)
                v = *(const uint4*)(xh + (((b * 128 + ih) * 128 + iw) * 256
                                          + ciblk * 32 + khalf * 16 + khi * 8));
            *(uint4*)(xst + (rk * 132 + col) * 24 + khi * 8) = v;
        }
        // stage weights: 36 groups x 64 rows x 16B, fully coalesced
        for (int idx = t; idx < 2304; idx += 256) {
            int g = idx >> 6, cor = idx & 63;
            *(uint4*)(wlds + (g * 64 + cor) * 8) =
                wsrc4[(ciblk * 36 + g) * 512 + bx * 64 + cor];
        }
        __syncthreads();
#pragma unroll
        for (int k9 = 0; k9 < 9; ++k9) {
            int kh = k9 / 3, kw = k9 % 3;
#pragma unroll
            for (int khalf = 0; khalf < 2; ++khalf) {
                int rk = kh * 2 + khalf;
                bf16x8 bfrag = *(const bf16x8*)(xst + (rk * 132 + wv * 32 + lo5 + kw) * 24 + hi1 * 8);
                const unsigned short* wbase = wlds + ((k9 * 2 + khalf) * 2 + hi1) * 512;
                bf16x8 a0 = *(const bf16x8*)(wbase + lo5 * 8);
                bf16x8 a1 = *(const bf16x8*)(wbase + (32 + lo5) * 8);
                acc0 = __builtin_amdgcn_mfma_f32_32x32x16_bf16(a0, bfrag, acc0, 0, 0, 0);
                acc1 = __builtin_amdgcn_mfma_f32_32x32x16_bf16(a1, bfrag, acc1, 0, 0, 0);
            }
        }
    }
    __syncthreads();

    // epilogue: bias (scale folded into weights) + ReLU -> ybuf[64][128]
    const int w = wv * 32 + lo5;
#pragma unroll
    for (int ct = 0; ct < 2; ++ct) {
        const f32x16& A = ct ? acc1 : acc0;
#pragma unroll
        for (int reg = 0; reg < 16; ++reg) {
            int cor = ct * 32 + (reg & 3) + 8 * (reg >> 2) + 4 * hi1;
            float v = fmaxf(A[reg] + shs[cor], 0.f);
            ybuf[cor * 128 + w] = v;
        }
    }
    __syncthreads();

    // row scans: rows 0..15 = L (reverse), 16..31 = R (forward)
    for (int rr = 0; rr < 8; ++rr) {
        int p = wv * 8 + rr;    // wave-uniform branch below
        float v0 = ybuf[p * 128 + 2 * lane];
        float v1 = ybuf[p * 128 + 2 * lane + 1];
        float a = fmaxf(v0, v1);
        if (p >= 16) {          // forward (max over w' <= w)
#pragma unroll
            for (int d = 1; d < 64; d <<= 1) {
                float o = __shfl_up(a, d);
                if (lane >= d) a = fmaxf(a, o);
            }
            float e = __shfl_up(a, 1);
            if (lane == 0) e = NEG_INF;
            float o0 = fmaxf(e, v0);
            float o1 = fmaxf(o0, v1);
            ybuf[p * 128 + 2 * lane]     = o0;
            ybuf[p * 128 + 2 * lane + 1] = o1;
        } else {                // reverse (max over w' >= w)
#pragma unroll
            for (int d = 1; d < 64; d <<= 1) {
                float o = __shfl_down(a, d);
                if (lane < 64 - d) a = fmaxf(a, o);
            }
            float e = __shfl_down(a, 1);
            if (lane == 63) e = NEG_INF;
            float o1 = fmaxf(e, v1);
            float o0 = fmaxf(o1, v0);
            ybuf[p * 128 + 2 * lane]     = o0;
            ybuf[p * 128 + 2 * lane + 1] = o1;
        }
    }
    __syncthreads();

    // lr sum -> sbuf2 NHWC; T/B raw -> ytb NHWC (all c-fastest, 32B segments)
    for (int idx = t; idx < 2048; idx += 256) {
        int cl = idx & 15, ww = idx >> 4;
        int base = ((b * 128 + h) * 128 + ww) * 128 + bx * 16 + cl;
        sbuf2[base] = f2bf(ybuf[cl * 128 + ww] + ybuf[(16 + cl) * 128 + ww]);
        ytbT[base]  = f2bf(ybuf[(32 + cl) * 128 + ww]);
        ytbB[base]  = f2bf(ybuf[(48 + cl) * 128 + ww]);
    }
}

// ---------------- column scans (T reverse, B forward), RMW sbuf2 ----
// grid (16 w-chunks, 4 c-chunks, 8 b). block tile: 32 c x 8 w columns.
template<int REV>
__global__ void __launch_bounds__(256)
k_colscan(const unsigned short* __restrict__ ytb, unsigned short* __restrict__ sbuf2)
{
    __shared__ float tile[8][8][33];    // [hh][w][c]
    const int t = threadIdx.x;
    const int w0 = blockIdx.x * 8, c0 = blockIdx.y * 32, b = blockIdx.z;
    const int sc = t & 31, sw = t >> 5;          // scan mapping
    const int rh = t >> 5, r5 = t & 31;          // rmw mapping
    const int rw = r5 >> 2, rcq = r5 & 3;
    float cum = NEG_INF;
    for (int step = 0; step < 16; ++step) {
        int h0 = REV ? 120 - step * 8 : step * 8;
        for (int q = 0; q < 8; ++q) {
            int hh = REV ? 7 - q : q;
            int hg = h0 + hh;
            float v = bf2f(ytb[((b * 128 + hg) * 128 + (w0 + sw)) * 128 + c0 + sc]);
            cum = fmaxf(cum, v);
            tile[hh][sw][sc] = cum;
        }
        __syncthreads();
        {
            int hg = h0 + rh;
            unsigned short* p = sbuf2 + ((b * 128 + hg) * 128 + w0 + rw) * 128 + c0 + rcq * 8;
            uint4 u = *(uint4*)p;
            unsigned short* us = (unsigned short*)&u;
#pragma unroll
            for (int j = 0; j < 8; ++j)
                us[j] = f2bf(bf2f(us[j]) + tile[rh][rw][rcq * 8 + j]);
            *(uint4*)p = u;
        }
        __syncthreads();
    }
}

// ---------------- final: conv3x3(sbuf2,128->256) + 1x1(xh,256->256) --
__global__ void __launch_bounds__(256, 2)
k_final(const unsigned short* __restrict__ sbuf2, const unsigned short* __restrict__ xh,
        const unsigned short* __restrict__ wpk2, const unsigned short* __restrict__ wpk1,
        const float* __restrict__ obF, float* __restrict__ out)
{
    __shared__ __align__(16) char smem[75136];
    unsigned short* xst  = (unsigned short*)smem;
    unsigned short* wlds = (unsigned short*)(smem + 38016);
    float* obs = (float*)(smem + 74880);

    const int t = threadIdx.x;
    const int bx = blockIdx.x, h = blockIdx.y, b = blockIdx.z;
    const int wv = t >> 6, lane = t & 63;
    const int lo5 = lane & 31, hi1 = lane >> 5;

    if (t < 64) obs[t] = obF[bx * 64 + t];

    f32x16 acc0, acc1;
#pragma unroll
    for (int i = 0; i < 16; ++i) { acc0[i] = 0.f; acc1[i] = 0.f; }

    // ---- conv 3x3 over sbuf2 (128 ci = 4 chunks) ----
    const uint4* w2src = (const uint4*)wpk2;
    for (int ciblk = 0; ciblk < 4; ++ciblk) {
        __syncthreads();
        for (int idx = t; idx < 1584; idx += 256) {
            int khi = idx & 1, tmp = idx >> 1;
            int col = tmp % 132, rk = tmp / 132;
            int r = rk >> 1, khalf = rk & 1;
            int ih = h + r - 1, iw = col - 1;
            uint4 v = make_uint4(0, 0, 0, 0);
            if (ih >= 0 && ih < 128 && iw >= 0 && iw < 128)
                v = *(const uint4*)(sbuf2 + (((b * 128 + ih) * 128 + iw) * 128
                                             + ciblk * 32 + khalf * 16 + khi * 8));
            *(uint4*)(xst + (rk * 132 + col) * 24 + khi * 8) = v;
        }
        for (int idx = t; idx < 2304; idx += 256) {
            int g = idx >> 6, cor = idx & 63;
            *(uint4*)(wlds + (g * 64 + cor) * 8) =
                w2src[(ciblk * 36 + g) * 256 + bx * 64 + cor];
        }
        __syncthreads();
#pragma unroll
        for (int k9 = 0; k9 < 9; ++k9) {
            int kh = k9 / 3, kw = k9 % 3;
#pragma unroll
            for (int khalf = 0; khalf < 2; ++khalf) {
                int rk = kh * 2 + khalf;
                bf16x8 bfrag = *(const bf16x8*)(xst + (rk * 132 + wv * 32 + lo5 + kw) * 24 + hi1 * 8);
                const unsigned short* wbase = wlds + ((k9 * 2 + khalf) * 2 + hi1) * 512;
                bf16x8 a0 = *(const bf16x8*)(wbase + lo5 * 8);
                bf16x8 a1 = *(const bf16x8*)(wbase + (32 + lo5) * 8);
                acc0 = __builtin_amdgcn_mfma_f32_32x32x16_bf16(a0, bfrag, acc0, 0, 0, 0);
                acc1 = __builtin_amdgcn_mfma_f32_32x32x16_bf16(a1, bfrag, acc1, 0, 0, 0);
            }
        }
    }

    // ---- 1x1 over xh (256 ci = 8 chunks), same accumulators ----
    const uint4* w1src = (const uint4*)wpk1;
    for (int ciblk = 0; ciblk < 8; ++ciblk) {
        __syncthreads();
        for (int idx = t; idx < 512; idx += 256) {
            int khi = idx & 1, tmp = idx >> 1;
            int col = tmp & 127, khalf = tmp >> 7;
            uint4 v = *(const uint4*)(xh + (((b * 128 + h) * 128 + col) * 256
                                            + ciblk * 32 + khalf * 16 + khi * 8));
            *(uint4*)(xst + (khalf * 132 + col) * 24 + khi * 8) = v;
        }
        for (int idx = t; idx < 256; idx += 256) {
            int g = idx >> 6, cor = idx & 63;
            *(uint4*)(wlds + (g * 64 + cor) * 8) =
                w1src[(ciblk * 4 + g) * 256 + bx * 64 + cor];
        }
        __syncthreads();
#pragma unroll
        for (int khalf = 0; khalf < 2; ++khalf) {
            bf16x8 bfrag = *(const bf16x8*)(xst + (khalf * 132 + wv * 32 + lo5) * 24 + hi1 * 8);
            const unsigned short* wbase = wlds + (khalf * 2 + hi1) * 512;
            bf16x8 a0 = *(const bf16x8*)(wbase + lo5 * 8);
            bf16x8 a1 = *(const bf16x8*)(wbase + (32 + lo5) * 8);
            acc0 = __builtin_amdgcn_mfma_f32_32x32x16_bf16(a0, bfrag, acc0, 0, 0, 0);
            acc1 = __builtin_amdgcn_mfma_f32_32x32x16_bf16(a1, bfrag, acc1, 0, 0, 0);
        }
    }

    // epilogue: + (o2+o1), ReLU, fp32 NCHW store
    const int w = wv * 32 + lo5;
#pragma unroll
    for (int ct = 0; ct < 2; ++ct) {
        const f32x16& A = ct ? acc1 : acc0;
#pragma unroll
        for (int reg = 0; reg < 16; ++reg) {
            int cor = ct * 32 + (reg & 3) + 8 * (reg >> 2) + 4 * hi1;
            float v = fmaxf(A[reg] + obs[cor], 0.f);
            out[((b * 256 + bx * 64 + cor) * 128 + h) * 128 + w] = v;
        }
    }
}

extern "C" void kernel_launch(void* const* d_in, const int* in_sizes, int n_in,
                              void* d_out, int out_size, void* d_ws, size_t ws_size,
                              hipStream_t stream)
{
    const float* x   = (const float*)d_in[0];
    const float* w_l = (const float*)d_in[1];
    const float* s_l = (const float*)d_in[2];
    const float* o_l = (const float*)d_in[3];
    const float* w_r = (const float*)d_in[4];
    const float* s_r = (const float*)d_in[5];
    const float* o_r = (const float*)d_in[6];
    const float* w_t = (const float*)d_in[7];
    const float* s_t = (const float*)d_in[8];
    const float* o_t = (const float*)d_in[9];
    const float* w_b = (const float*)d_in[10];
    const float* s_b = (const float*)d_in[11];
    const float* o_b = (const float*)d_in[12];
    const float* w2  = (const float*)d_in[13];
    const float* s2  = (const float*)d_in[14];
    const float* o2  = (const float*)d_in[15];
    const float* w1  = (const float*)d_in[16];
    const float* s1  = (const float*)d_in[17];
    const float* o1  = (const float*)d_in[18];
    float* out = (float*)d_out;
    char*  ws  = (char*)d_ws;

    // ws layout (bytes)
    unsigned short* xh    = (unsigned short*)(ws + 0);            // 64 MiB
    unsigned short* sbuf2 = (unsigned short*)(ws + 67108864);     // 32 MiB
    unsigned short* wpkBR = (unsigned short*)(ws + 100663296);    // 2.25 MiB
    unsigned short* wpk2  = (unsigned short*)(ws + 103022592);    // 576 KiB
    unsigned short* wpk1  = (unsigned short*)(ws + 103612416);    // 128 KiB
    float* shF = (float*)(ws + 103743488);                         // 2 KiB
    float* obF = (float*)(ws + 103745536);                         // 1 KiB

    // d_out (128 MiB fp32) doubles as scratch for T/B conv outputs (64 MiB bf16),
    // consumed by colscans before k_final overwrites the whole output.
    unsigned short* ytbT = (unsigned short*)d_out;
    unsigned short* ytbB = ytbT + 16777216;

    dim3 blk(256);
    k_xpose<<<dim3(4, 128, 8), blk, 0, stream>>>(x, xh);
    k_wpack<<<dim3(6019), blk, 0, stream>>>(w_l, s_l, o_l, w_r, s_r, o_r,
                                            w_t, s_t, o_t, w_b, s_b, o_b,
                                            w2, s2, o2, w1, s1, o1,
                                            wpkBR, wpk2, wpk1, shF, obF);
    k_brconv<<<dim3(8, 128, 8), blk, 0, stream>>>(xh, wpkBR, shF, sbuf2, ytbT, ytbB);
    k_colscan<1><<<dim3(16, 4, 8), blk, 0, stream>>>(ytbT, sbuf2);
    k_colscan<0><<<dim3(16, 4, 8), blk, 0, stream>>>(ytbB, sbuf2);
    k_final<<<dim3(4, 128, 8), blk, 0, stream>>>(sbuf2, xh, wpk2, wpk1, obF, out);
}

// Round 4
// 797.271 us; speedup vs baseline: 10.3925x; 1.7096x over previous
//
#include <hip/hip_runtime.h>

#define NEG_INF (-3.402823466e+38f)

typedef __bf16 bf16x8 __attribute__((ext_vector_type(8)));
typedef float  f32x16 __attribute__((ext_vector_type(16)));

__device__ __forceinline__ unsigned short f2bf(float f){
    unsigned u = __builtin_bit_cast(unsigned, f);
    u += 0x7fffu + ((u >> 16) & 1u);
    return (unsigned short)(u >> 16);
}
__device__ __forceinline__ float bf2f(unsigned short h){
    unsigned u = ((unsigned)h) << 16;
    return __builtin_bit_cast(float, u);
}

#if defined(__has_builtin)
#if __has_builtin(__builtin_amdgcn_global_load_lds)
#define ASYNC_CP 1
#endif
#endif

// async global->LDS: per-lane g, wave-uniform lbase; lane i lands at lbase + i*16B
__device__ __forceinline__ void gl_lds(const unsigned short* g, unsigned short* lbase, int lane) {
#ifdef ASYNC_CP
    __builtin_amdgcn_global_load_lds(
        (const __attribute__((address_space(1))) unsigned int*)g,
        (__attribute__((address_space(3))) unsigned int*)lbase, 16, 0, 0);
#else
    *(uint4*)(lbase + (size_t)lane * 8) = *(const uint4*)g;
#endif
}

// ---------------- prep: x fp32 NCHW -> bf16 NHWC -------------------
__global__ void __launch_bounds__(256)
k_xpose(const float* __restrict__ x, unsigned short* __restrict__ xh)
{
    __shared__ float tile[64 * 129];
    const int t = threadIdx.x;
    const int ci0 = blockIdx.x * 64, h = blockIdx.y, b = blockIdx.z;
    const float4* src = (const float4*)x;
#pragma unroll
    for (int i = 0; i < 8; ++i) {
        int idx = t + i * 256;
        int ci = idx >> 5, w4 = idx & 31;
        float4 v = src[((b * 256 + ci0 + ci) * 128 + h) * 32 + w4];
        tile[ci * 129 + w4 * 4 + 0] = v.x;
        tile[ci * 129 + w4 * 4 + 1] = v.y;
        tile[ci * 129 + w4 * 4 + 2] = v.z;
        tile[ci * 129 + w4 * 4 + 3] = v.w;
    }
    __syncthreads();
    unsigned* dst = (unsigned*)xh;
#pragma unroll
    for (int i = 0; i < 16; ++i) {
        int idx = t + i * 256;
        int w = idx >> 5, cp = idx & 31;
        float lo = tile[(cp * 2 + 0) * 129 + w];
        float hi = tile[(cp * 2 + 1) * 129 + w];
        dst[((b * 128 + h) * 128 + w) * 128 + (ci0 >> 1) + cp] =
            (unsigned)f2bf(lo) | ((unsigned)f2bf(hi) << 16);
    }
}

// ---------------- prep: weight packing (BN scale folded) -----------
// wpkBR: [ciblk16][k9 9][khi 2][p 512][8ci]   p=(c>>4)*64+br*16+(c&15)
// wpk2 : [ciblk 8][k9 9][khi 2][c 256][8ci]
// wpk1 : [ciblk16][khi 2][c 256][8ci]
__global__ void __launch_bounds__(256)
k_wpack(const float* __restrict__ wl, const float* __restrict__ sl, const float* __restrict__ ol,
        const float* __restrict__ wr, const float* __restrict__ sr, const float* __restrict__ orr,
        const float* __restrict__ wt, const float* __restrict__ st, const float* __restrict__ ot,
        const float* __restrict__ wb, const float* __restrict__ sb, const float* __restrict__ ob,
        const float* __restrict__ w2, const float* __restrict__ s2, const float* __restrict__ o2,
        const float* __restrict__ w1, const float* __restrict__ s1, const float* __restrict__ o1,
        unsigned short* __restrict__ wpkBR, unsigned short* __restrict__ wpk2,
        unsigned short* __restrict__ wpk1, float* __restrict__ shF, float* __restrict__ obF)
{
    int i = blockIdx.x * 256 + threadIdx.x;
    if (i < 1179648) {
        int br = i / 294912, r = i % 294912;
        int c = r / 2304, r2 = r % 2304, ci = r2 / 9, k9 = r2 % 9;
        const float* wp = br == 0 ? wl : br == 1 ? wr : br == 2 ? wt : wb;
        const float* sp = br == 0 ? sl : br == 1 ? sr : br == 2 ? st : sb;
        float v = wp[r] * sp[c];
        int p = (c >> 4) * 64 + br * 16 + (c & 15);
        wpkBR[(((((ci >> 4) * 9 + k9) * 2 + ((ci >> 3) & 1)) * 512 + p) * 8) + (ci & 7)] = f2bf(v);
    } else if (i < 1474560) {
        int j = i - 1179648;
        int c = j / 1152, r2 = j % 1152, ci = r2 / 9, k9 = r2 % 9;
        wpk2[(((((ci >> 4) * 9 + k9) * 2 + ((ci >> 3) & 1)) * 256 + c) * 8) + (ci & 7)] = f2bf(w2[j] * s2[c]);
    } else if (i < 1540096) {
        int j = i - 1474560;
        int c = j >> 8, ci = j & 255;
        wpk1[((((ci >> 4) * 2 + ((ci >> 3) & 1)) * 256 + c) * 8) + (ci & 7)] = f2bf(w1[j] * s1[c]);
    } else if (i < 1540608) {
        int p = i - 1540096;
        int br = (p >> 4) & 3, c = (p >> 6) * 16 + (p & 15);
        const float* op = br == 0 ? ol : br == 1 ? orr : br == 2 ? ot : ob;
        shF[p] = op[c];
    } else if (i < 1540864) {
        int c = i - 1540608;
        obF[c] = o2[c] + o1[c];
    }
}

// ---------------- branch conv: all 4 branches, 4 rows/block --------
// grid (8 bx, 32 hstrip, 8 b), 256 thr. Wave wv = output row h0+wv.
// M=64 (4br x 16ch), per-wave N=128 (full w), K=2304 (16ci chunks x 9 k9).
// LDS: xin [rk 12][col 132][8ci] 25344B | wbuf [18][64][8ci] 18432B | shs 256B
#define XIN_SH 12672
#define WBUF_SH 9216
__global__ void __launch_bounds__(256, 2)
k_brconv(const unsigned short* __restrict__ xh, const unsigned short* __restrict__ wpkBR,
         const float* __restrict__ shF, unsigned short* __restrict__ sbuf2,
         unsigned short* __restrict__ ytbT, unsigned short* __restrict__ ytbB)
{
    __shared__ __align__(16) unsigned short smem[XIN_SH + WBUF_SH + 128];
    unsigned short* xin  = smem;
    unsigned short* wbuf = smem + XIN_SH;
    float* shs = (float*)(smem + XIN_SH + WBUF_SH);

    const int t = threadIdx.x;
    const int bx = blockIdx.x, h0 = blockIdx.y << 2, b = blockIdx.z;
    const int wv = t >> 6, lane = t & 63;
    const int lo5 = lane & 31, hi1 = lane >> 5;
    const int hi32 = lane & 32;

    if (t < 64) shs[t] = shF[bx * 64 + t];
    // zero xin once: halo cols + OOB rows stay zero forever
    for (int idx = t; idx < 1584; idx += 256) {
        uint4 z = make_uint4(0, 0, 0, 0);
        *(uint4*)(xin + idx * 8) = z;
    }

    f32x16 acc[2][4];
#pragma unroll
    for (int ct = 0; ct < 2; ++ct)
#pragma unroll
        for (int nb = 0; nb < 4; ++nb)
#pragma unroll
            for (int i = 0; i < 16; ++i) acc[ct][nb][i] = 0.f;

    for (int ciblk = 0; ciblk < 16; ++ciblk) {
        __syncthreads();
        // input: 24 segs (r 0..5, khi, half): cols 1..128 loaded, halo stays 0
        for (int s = wv; s < 24; s += 4) {
            int r = s >> 2, khi = (s >> 1) & 1, half = s & 1;
            int ih = h0 - 1 + r;
            if (ih >= 0 && ih < 128) {
                const unsigned short* g = xh + (((size_t)(b * 128 + ih) * 128 + half * 64 + lane) * 256)
                                             + ciblk * 16 + khi * 8;
                unsigned short* l = xin + ((r * 2 + khi) * 132 + 1 + half * 64) * 8;
                gl_lds(g, l, lane);
            }
        }
        // weights: 18 segs (k9, khi), lane = m, fully contiguous
        for (int s = wv; s < 18; s += 4) {
            const unsigned short* g = wpkBR + ((size_t)(ciblk * 18 + s) * 512 + bx * 64 + lane) * 8;
            gl_lds(g, wbuf + s * 512, lane);
        }
        __syncthreads();
#pragma unroll
        for (int k9 = 0; k9 < 9; ++k9) {
            const int kh = k9 / 3, kw = k9 % 3;
            bf16x8 a0 = *(const bf16x8*)(wbuf + ((k9 * 2 + hi1) * 64 + lo5) * 8);
            bf16x8 a1 = *(const bf16x8*)(wbuf + ((k9 * 2 + hi1) * 64 + 32 + lo5) * 8);
#pragma unroll
            for (int nb = 0; nb < 4; ++nb) {
                bf16x8 bf = *(const bf16x8*)(xin + (((wv + kh) * 2 + hi1) * 132 + nb * 32 + lo5 + kw) * 8);
                acc[0][nb] = __builtin_amdgcn_mfma_f32_32x32x16_bf16(a0, bf, acc[0][nb], 0, 0, 0);
                acc[1][nb] = __builtin_amdgcn_mfma_f32_32x32x16_bf16(a1, bf, acc[1][nb], 0, 0, 0);
            }
        }
    }
    __syncthreads();   // LDS free for repack

    unsigned short* pbw = smem + wv * 3072;   // [w 128][c pad 24] bf16, per-wave
    const int hg = h0 + wv;

    // ---- L (ct0, regs 0..7): bias+relu then reverse cummax over w ----
#pragma unroll
    for (int r = 0; r < 8; ++r) {
        const int m = (r & 3) + 8 * (r >> 2) + 4 * hi1;
        const float shv = shs[m];
        float carry = NEG_INF;
#pragma unroll
        for (int nn = 3; nn >= 0; --nn) {
            float a = fmaxf(acc[0][nn][r] + shv, 0.f);
#pragma unroll
            for (int d = 1; d < 32; d <<= 1) {
                float o = __shfl_down(a, d);
                if (lo5 < 32 - d) a = fmaxf(a, o);
            }
            a = fmaxf(a, carry);
            carry = __shfl(a, hi32);
            acc[0][nn][r] = a;
        }
    }
    // ---- R (ct0, regs 8..15): forward cummax ----
#pragma unroll
    for (int r = 8; r < 16; ++r) {
        const int m = 16 + (r & 3) + 8 * ((r >> 2) & 1) + 4 * hi1;
        const float shv = shs[m];
        float carry = NEG_INF;
#pragma unroll
        for (int nn = 0; nn < 4; ++nn) {
            float a = fmaxf(acc[0][nn][r] + shv, 0.f);
#pragma unroll
            for (int d = 1; d < 32; d <<= 1) {
                float o = __shfl_up(a, d);
                if (lo5 >= d) a = fmaxf(a, o);
            }
            a = fmaxf(a, carry);
            carry = __shfl(a, hi32 | 31);
            acc[0][nn][r] = a;
        }
    }
    // ---- sum L+R -> pbw -> sbuf2 ----
#pragma unroll
    for (int r = 0; r < 8; ++r) {
        const int c16 = (r & 3) + 8 * (r >> 2) + 4 * hi1;
#pragma unroll
        for (int nn = 0; nn < 4; ++nn)
            pbw[(nn * 32 + lo5) * 24 + c16] = f2bf(acc[0][nn][r] + acc[0][nn][r + 8]);
    }
    {
        unsigned short* gdst = sbuf2 + ((size_t)(b * 128 + hg) * 128) * 128 + bx * 16;
#pragma unroll
        for (int i = 0; i < 4; ++i) {    // 256 uint4 segs = 128 w x 16 c
            int idx = lane + i * 64;
            int w = idx >> 1, part = idx & 1;
            *(uint4*)(gdst + (size_t)w * 128 + part * 8) = *(const uint4*)(pbw + w * 24 + part * 8);
        }
    }
    // ---- T (ct1, regs 0..7): bias+relu -> ytbT ----
#pragma unroll
    for (int r = 0; r < 8; ++r) {
        const int c16 = (r & 3) + 8 * (r >> 2) + 4 * hi1;
        const float shv = shs[32 + c16];
#pragma unroll
        for (int nn = 0; nn < 4; ++nn)
            pbw[(nn * 32 + lo5) * 24 + c16] = f2bf(fmaxf(acc[1][nn][r] + shv, 0.f));
    }
    {
        unsigned short* gdst = ytbT + ((size_t)(b * 128 + hg) * 128) * 128 + bx * 16;
#pragma unroll
        for (int i = 0; i < 4; ++i) {
            int idx = lane + i * 64;
            int w = idx >> 1, part = idx & 1;
            *(uint4*)(gdst + (size_t)w * 128 + part * 8) = *(const uint4*)(pbw + w * 24 + part * 8);
        }
    }
    // ---- B (ct1, regs 8..15): bias+relu -> ytbB ----
#pragma unroll
    for (int r = 8; r < 16; ++r) {
        const int c16 = (r & 3) + 8 * ((r >> 2) & 1) + 4 * hi1;
        const float shv = shs[48 + c16];
#pragma unroll
        for (int nn = 0; nn < 4; ++nn)
            pbw[(nn * 32 + lo5) * 24 + c16] = f2bf(fmaxf(acc[1][nn][r] + shv, 0.f));
    }
    {
        unsigned short* gdst = ytbB + ((size_t)(b * 128 + hg) * 128) * 128 + bx * 16;
#pragma unroll
        for (int i = 0; i < 4; ++i) {
            int idx = lane + i * 64;
            int w = idx >> 1, part = idx & 1;
            *(uint4*)(gdst + (size_t)w * 128 + part * 8) = *(const uint4*)(pbw + w * 24 + part * 8);
        }
    }
}

// ---------------- column scans (T reverse, B forward), RMW sbuf2 ----
template<int REV>
__global__ void __launch_bounds__(256)
k_colscan(const unsigned short* __restrict__ ytb, unsigned short* __restrict__ sbuf2)
{
    __shared__ float tile[8][8][33];
    const int t = threadIdx.x;
    const int w0 = blockIdx.x * 8, c0 = blockIdx.y * 32, b = blockIdx.z;
    const int sc = t & 31, sw = t >> 5;
    const int rh = t >> 5, r5 = t & 31;
    const int rw = r5 >> 2, rcq = r5 & 3;
    float cum = NEG_INF;
    for (int step = 0; step < 16; ++step) {
        int h0 = REV ? 120 - step * 8 : step * 8;
        for (int q = 0; q < 8; ++q) {
            int hh = REV ? 7 - q : q;
            int hg = h0 + hh;
            float v = bf2f(ytb[((b * 128 + hg) * 128 + (w0 + sw)) * 128 + c0 + sc]);
            cum = fmaxf(cum, v);
            tile[hh][sw][sc] = cum;
        }
        __syncthreads();
        {
            int hg = h0 + rh;
            unsigned short* p = sbuf2 + ((b * 128 + hg) * 128 + w0 + rw) * 128 + c0 + rcq * 8;
            uint4 u = *(uint4*)p;
            unsigned short* us = (unsigned short*)&u;
#pragma unroll
            for (int j = 0; j < 8; ++j)
                us[j] = f2bf(bf2f(us[j]) + tile[rh][rw][rcq * 8 + j]);
            *(uint4*)p = u;
        }
        __syncthreads();
    }
}

// ---------------- final: conv3x3(sbuf2,128->256) + 1x1(xh) ----------
// grid (4 bx, 32 hstrip, 8 b). Same tile structure as k_brconv.
__global__ void __launch_bounds__(256, 2)
k_final(const unsigned short* __restrict__ sbuf2, const unsigned short* __restrict__ xh,
        const unsigned short* __restrict__ wpk2, const unsigned short* __restrict__ wpk1,
        const float* __restrict__ obF, float* __restrict__ out)
{
    __shared__ __align__(16) unsigned short smem[XIN_SH + WBUF_SH + 128];
    unsigned short* xin  = smem;
    unsigned short* wbuf = smem + XIN_SH;
    float* obs = (float*)(smem + XIN_SH + WBUF_SH);

    const int t = threadIdx.x;
    const int bx = blockIdx.x, h0 = blockIdx.y << 2, b = blockIdx.z;
    const int wv = t >> 6, lane = t & 63;
    const int lo5 = lane & 31, hi1 = lane >> 5;

    if (t < 64) obs[t] = obF[bx * 64 + t];
    for (int idx = t; idx < 1584; idx += 256) {
        uint4 z = make_uint4(0, 0, 0, 0);
        *(uint4*)(xin + idx * 8) = z;
    }

    f32x16 acc[2][4];
#pragma unroll
    for (int ct = 0; ct < 2; ++ct)
#pragma unroll
        for (int nb = 0; nb < 4; ++nb)
#pragma unroll
            for (int i = 0; i < 16; ++i) acc[ct][nb][i] = 0.f;

    // ---- 3x3 over sbuf2: 8 ci-chunks ----
    for (int ciblk = 0; ciblk < 8; ++ciblk) {
        __syncthreads();
        for (int s = wv; s < 24; s += 4) {
            int r = s >> 2, khi = (s >> 1) & 1, half = s & 1;
            int ih = h0 - 1 + r;
            if (ih >= 0 && ih < 128) {
                const unsigned short* g = sbuf2 + (((size_t)(b * 128 + ih) * 128 + half * 64 + lane) * 128)
                                                 + ciblk * 16 + khi * 8;
                unsigned short* l = xin + ((r * 2 + khi) * 132 + 1 + half * 64) * 8;
                gl_lds(g, l, lane);
            }
        }
        for (int s = wv; s < 18; s += 4) {
            const unsigned short* g = wpk2 + ((size_t)(ciblk * 18 + s) * 256 + bx * 64 + lane) * 8;
            gl_lds(g, wbuf + s * 512, lane);
        }
        __syncthreads();
#pragma unroll
        for (int k9 = 0; k9 < 9; ++k9) {
            const int kh = k9 / 3, kw = k9 % 3;
            bf16x8 a0 = *(const bf16x8*)(wbuf + ((k9 * 2 + hi1) * 64 + lo5) * 8);
            bf16x8 a1 = *(const bf16x8*)(wbuf + ((k9 * 2 + hi1) * 64 + 32 + lo5) * 8);
#pragma unroll
            for (int nb = 0; nb < 4; ++nb) {
                bf16x8 bf = *(const bf16x8*)(xin + (((wv + kh) * 2 + hi1) * 132 + nb * 32 + lo5 + kw) * 8);
                acc[0][nb] = __builtin_amdgcn_mfma_f32_32x32x16_bf16(a0, bf, acc[0][nb], 0, 0, 0);
                acc[1][nb] = __builtin_amdgcn_mfma_f32_32x32x16_bf16(a1, bf, acc[1][nb], 0, 0, 0);
            }
        }
    }
    // ---- 1x1 over xh: 16 ci-chunks ----
    for (int ciblk = 0; ciblk < 16; ++ciblk) {
        __syncthreads();
        for (int s = wv; s < 16; s += 4) {
            int wr = s >> 2, khi = (s >> 1) & 1, half = s & 1;
            int ih = h0 + wr;
            const unsigned short* g = xh + (((size_t)(b * 128 + ih) * 128 + half * 64 + lane) * 256)
                                         + ciblk * 16 + khi * 8;
            unsigned short* l = xin + ((wr * 2 + khi) * 132 + 1 + half * 64) * 8;
            gl_lds(g, l, lane);
        }
        for (int s = wv; s < 2; s += 4) {
            const unsigned short* g = wpk1 + ((size_t)(ciblk * 2 + s) * 256 + bx * 64 + lane) * 8;
            gl_lds(g, wbuf + s * 512, lane);
        }
        __syncthreads();
        {
            bf16x8 a0 = *(const bf16x8*)(wbuf + (hi1 * 64 + lo5) * 8);
            bf16x8 a1 = *(const bf16x8*)(wbuf + (hi1 * 64 + 32 + lo5) * 8);
#pragma unroll
            for (int nb = 0; nb < 4; ++nb) {
                bf16x8 bf = *(const bf16x8*)(xin + ((wv * 2 + hi1) * 132 + 1 + nb * 32 + lo5) * 8);
                acc[0][nb] = __builtin_amdgcn_mfma_f32_32x32x16_bf16(a0, bf, acc[0][nb], 0, 0, 0);
                acc[1][nb] = __builtin_amdgcn_mfma_f32_32x32x16_bf16(a1, bf, acc[1][nb], 0, 0, 0);
            }
        }
    }
    __syncthreads();

    // epilogue: bias + relu, fp32 NCHW stores (coalesced 32-lane segments)
    const int hg = h0 + wv;
#pragma unroll
    for (int ct = 0; ct < 2; ++ct)
#pragma unroll
        for (int r = 0; r < 16; ++r) {
            const int m = ct * 32 + (r & 3) + 8 * (r >> 2) + 4 * hi1;
            const float bias = obs[m];
#pragma unroll
            for (int nb = 0; nb < 4; ++nb)
                out[((size_t)(b * 256 + bx * 64 + m) * 128 + hg) * 128 + nb * 32 + lo5] =
                    fmaxf(acc[ct][nb][r] + bias, 0.f);
        }
}

extern "C" void kernel_launch(void* const* d_in, const int* in_sizes, int n_in,
                              void* d_out, int out_size, void* d_ws, size_t ws_size,
                              hipStream_t stream)
{
    const float* x   = (const float*)d_in[0];
    const float* w_l = (const float*)d_in[1];
    const float* s_l = (const float*)d_in[2];
    const float* o_l = (const float*)d_in[3];
    const float* w_r = (const float*)d_in[4];
    const float* s_r = (const float*)d_in[5];
    const float* o_r = (const float*)d_in[6];
    const float* w_t = (const float*)d_in[7];
    const float* s_t = (const float*)d_in[8];
    const float* o_t = (const float*)d_in[9];
    const float* w_b = (const float*)d_in[10];
    const float* s_b = (const float*)d_in[11];
    const float* o_b = (const float*)d_in[12];
    const float* w2  = (const float*)d_in[13];
    const float* s2  = (const float*)d_in[14];
    const float* o2  = (const float*)d_in[15];
    const float* w1  = (const float*)d_in[16];
    const float* s1  = (const float*)d_in[17];
    const float* o1  = (const float*)d_in[18];
    float* out = (float*)d_out;
    char*  ws  = (char*)d_ws;

    unsigned short* xh    = (unsigned short*)(ws + 0);            // 64 MiB
    unsigned short* sbuf2 = (unsigned short*)(ws + 67108864);     // 32 MiB
    unsigned short* wpkBR = (unsigned short*)(ws + 100663296);    // 2.25 MiB
    unsigned short* wpk2  = (unsigned short*)(ws + 103022592);    // 576 KiB
    unsigned short* wpk1  = (unsigned short*)(ws + 103612416);    // 128 KiB
    float* shF = (float*)(ws + 103743488);
    float* obF = (float*)(ws + 103745536);

    unsigned short* ytbT = (unsigned short*)d_out;   // d_out as scratch (bf16, 2x32MiB)
    unsigned short* ytbB = ytbT + 16777216;

    dim3 blk(256);
    k_xpose<<<dim3(4, 128, 8), blk, 0, stream>>>(x, xh);
    k_wpack<<<dim3(6019), blk, 0, stream>>>(w_l, s_l, o_l, w_r, s_r, o_r,
                                            w_t, s_t, o_t, w_b, s_b, o_b,
                                            w2, s2, o2, w1, s1, o1,
                                            wpkBR, wpk2, wpk1, shF, obF);
    k_brconv<<<dim3(8, 32, 8), blk, 0, stream>>>(xh, wpkBR, shF, sbuf2, ytbT, ytbB);
    k_colscan<1><<<dim3(16, 4, 8), blk, 0, stream>>>(ytbT, sbuf2);
    k_colscan<0><<<dim3(16, 4, 8), blk, 0, stream>>>(ytbB, sbuf2);
    k_final<<<dim3(4, 32, 8), blk, 0, stream>>>(sbuf2, xh, wpk2, wpk1, obF, out);
}